// Round 8
// baseline (200.436 us; speedup 1.0000x reference)
//
#include <hip/hip_runtime.h>
#include <hip/hip_bf16.h>
#include <stdint.h>

using bf16 = __hip_bfloat16;
typedef __attribute__((ext_vector_type(8))) short short8;
typedef __attribute__((ext_vector_type(4))) short short4b;
typedef __attribute__((ext_vector_type(4))) float f32x4;
typedef __attribute__((ext_vector_type(4))) unsigned int u32x4;

#if __has_builtin(__builtin_amdgcn_exp2f)
#define EXP2(x) __builtin_amdgcn_exp2f(x)
#else
#define EXP2(x) exp2f(x)
#endif

__device__ __forceinline__ short8 load8(const bf16* p) {
  return *reinterpret_cast<const short8*>(p);
}
__device__ __forceinline__ short f2b(float f) {
  return __builtin_bit_cast(short, __float2bfloat16(f));
}
// hardware packed f32->bf16 pair conversion (lo -> low 16b). Only used for
// the attention P tile: values in [0,1], and the same rounding feeds both
// the PV numerator and the l-sum denominator, so the mode change cancels.
__device__ __forceinline__ unsigned int cvtpk(float lo, float hi) {
  unsigned int r;
  asm("v_cvt_pk_bf16_f32 %0, %1, %2" : "=v"(r) : "v"(lo), "v"(hi));
  return r;
}
// Masked-keep multiply: Mbits stores KEEP bits (inverted mask). One sbfe
// (sign-extend the keep bit to 0 / 0xFFFFFFFF) + one AND = 2 VALU per
// element, vs bfe+cmp+cndmask (3) for the ternary form.
__device__ __forceinline__ float keepmul(float e, unsigned w, int pos) {
#if __has_builtin(__builtin_amdgcn_sbfe)
  unsigned km = (unsigned)__builtin_amdgcn_sbfe((int)w, pos, 1);
  return __builtin_bit_cast(float, __builtin_bit_cast(unsigned, e) & km);
#else
  return ((w >> pos) & 1u) ? e : 0.f;  // keep-bit semantics
#endif
}
__device__ __forceinline__ void asy16(const bf16* g, bf16* l) {
  __builtin_amdgcn_global_load_lds(
      (const __attribute__((address_space(1))) void*)g,
      (__attribute__((address_space(3))) void*)l, 16, 0, 0);
}

// K fragment-order layout (per bh, per kt tile of 64 keys):
//   Kperm[((kc*2+half)*4+g)*128 + r*8 + j] = K[key=kc*16+r][d=half*32+8g+j]
// V fragment-order layout (PV contraction permuted by pi):
//   Vperm[((half*4+dvs)*4+g)*128 + r*8 + j] = V[dv=dvs*16+r][k=half*32+pi(g,j)]
//   pi(g,j) = (j>>2)*16 + 4g + (j&3)
// Both are 4096 elements per (bh,kt); staging to LDS is a linear 8KB copy.

// ---------------- fused prep kernel ----------------
// blocks [0,4096): x f32->bf16 ; [4096,4352): LDS-tiled weight transpose ;
// [4352,20736): mask bit-pack (stored INVERTED: bit=1 means keep).
__global__ void k_prep(const float4* __restrict__ x, ushort4* __restrict__ xb,
                       const float* __restrict__ Wq, const float* __restrict__ Wk,
                       const float* __restrict__ Wv, const float* __restrict__ Wo,
                       bf16* __restrict__ Wcat, bf16* __restrict__ Wot,
                       const int4* __restrict__ m4,
                       unsigned long long* __restrict__ bits) {
  int blk = blockIdx.x;
  const int tid = threadIdx.x;
  if (blk < 4096) {
    int i = blk * 256 + tid;
    float4 v = x[i];
    ushort4 o;
    o.x = (unsigned short)f2b(v.x);
    o.y = (unsigned short)f2b(v.y);
    o.z = (unsigned short)f2b(v.z);
    o.w = (unsigned short)f2b(v.w);
    xb[i] = o;
  } else if (blk < 4352) {
    int t = blk - 4096;
    __shared__ float T[64][65];
    if (t < 192) {
      // W{q,k,v}[h][512][64] -> Wcat[(which*512+h*64+dk)][d], 64x64 d-tiles
      int which = t >> 6;
      int h = (t >> 3) & 7, dt = t & 7;
      const float* W = (which == 0) ? Wq : ((which == 1) ? Wk : Wv);
#pragma unroll
      for (int p = 0; p < 4; ++p) {
        int row = p * 16 + (tid >> 4);
        float4 v = *(const float4*)(W + (size_t)(h * 512 + dt * 64 + row) * 64 +
                                    (tid & 15) * 4);
        T[row][(tid & 15) * 4 + 0] = v.x;
        T[row][(tid & 15) * 4 + 1] = v.y;
        T[row][(tid & 15) * 4 + 2] = v.z;
        T[row][(tid & 15) * 4 + 3] = v.w;
      }
      __syncthreads();
      float scale = (which == 0) ? 0.18033688011112042f : 1.0f;  // 0.125*log2e
      int jj = tid >> 2, i0 = (tid & 3) * 16;
#pragma unroll
      for (int q = 0; q < 2; ++q) {
        short8 o;
#pragma unroll
        for (int e = 0; e < 8; ++e) o[e] = f2b(T[i0 + q * 8 + e][jj] * scale);
        *(short8*)(Wcat + (size_t)(which * 512 + h * 64 + jj) * 512 + dt * 64 +
                   i0 + q * 8) = o;
      }
    } else {
      // Wo[h][64][512] -> Wot[e][h*64+v], 64x64 e-tiles
      int t2 = t - 192;
      int h = t2 >> 3, et = t2 & 7;
#pragma unroll
      for (int p = 0; p < 4; ++p) {
        int row = p * 16 + (tid >> 4);
        float4 v = *(const float4*)(Wo + (size_t)(h * 64 + row) * 512 + et * 64 +
                                    (tid & 15) * 4);
        T[row][(tid & 15) * 4 + 0] = v.x;
        T[row][(tid & 15) * 4 + 1] = v.y;
        T[row][(tid & 15) * 4 + 2] = v.z;
        T[row][(tid & 15) * 4 + 3] = v.w;
      }
      __syncthreads();
      int jj = tid >> 2, i0 = (tid & 3) * 16;
#pragma unroll
      for (int q = 0; q < 2; ++q) {
        short8 o;
#pragma unroll
        for (int e = 0; e < 8; ++e) o[e] = f2b(T[i0 + q * 8 + e][jj]);
        *(short8*)(Wot + (size_t)(et * 64 + jj) * 512 + h * 64 + i0 + q * 8) = o;
      }
    }
  } else {
    int i = (blk - 4352) * 256 + tid;
    int4 v = m4[i];
    unsigned int nib = (unsigned)(v.x != 0) | ((unsigned)(v.y != 0) << 1) |
                       ((unsigned)(v.z != 0) << 2) | ((unsigned)(v.w != 0) << 3);
    unsigned long long w = (unsigned long long)nib << (4 * (tid & 15));
    w |= __shfl_xor(w, 1);
    w |= __shfl_xor(w, 2);
    w |= __shfl_xor(w, 4);
    w |= __shfl_xor(w, 8);
    if ((tid & 15) == 0) bits[i >> 4] = ~w;  // inverted: 1 = keep
  }
}

// ---------------- 128x128 GEMM core, BK=32 double-buffered ----------------
__device__ __forceinline__ void gemm128(const bf16* __restrict__ A,
                                        const bf16* __restrict__ Bt,
                                        bf16* As, bf16* Bs,
                                        int rowBase, int colBase,
                                        f32x4 acc[4][4]) {
  const int tid = threadIdx.x;
  const int lane = tid & 63, w = tid >> 6;
  const int g = lane >> 4, r = lane & 15;

  auto stage = [&](int buf, int s) {
#pragma unroll
    for (int p = 0; p < 2; ++p) {
      int c = p * 256 + tid;
      int row = c >> 2, gr = c & 3, sg = gr ^ (row & 3);
      asy16(A + (size_t)(rowBase + row) * 512 + s * 32 + sg * 8,
            As + buf * 4096 + c * 8);
    }
#pragma unroll
    for (int p = 0; p < 2; ++p) {
      int c = p * 256 + tid;
      int row = c >> 2, gr = c & 3, sg = gr ^ (row & 3);
      asy16(Bt + (size_t)(colBase + row) * 512 + s * 32 + sg * 8,
            Bs + buf * 4096 + c * 8);
    }
  };

  stage(0, 0);
  int buf = 0;
  const int rbl = (w >> 1) * 64, cbl = (w & 1) * 64;
  for (int s = 0; s < 16; ++s) {
    __syncthreads();
    if (s < 15) stage(buf ^ 1, s + 1);
    const bf16* a0 = As + buf * 4096;
    const bf16* b0 = Bs + buf * 4096;
    short8 af[4], bfr[4];
#pragma unroll
    for (int mt = 0; mt < 4; ++mt) {
      int row = rbl + mt * 16 + r;
      af[mt] = load8(a0 + (row * 4 + (g ^ (row & 3))) * 8);
    }
#pragma unroll
    for (int nt = 0; nt < 4; ++nt) {
      int col = cbl + nt * 16 + r;
      bfr[nt] = load8(b0 + (col * 4 + (g ^ (col & 3))) * 8);
    }
#pragma unroll
    for (int mt = 0; mt < 4; ++mt)
#pragma unroll
      for (int nt = 0; nt < 4; ++nt)
        acc[mt][nt] = __builtin_amdgcn_mfma_f32_16x16x32_bf16(
            af[mt], bfr[nt], acc[mt][nt], 0, 0, 0);
    buf ^= 1;
  }
}

// ---------------- 64x128 GEMM core (for k_proj_out), BK=32 dbuf ----------
__device__ __forceinline__ void gemm64x128(const bf16* __restrict__ A,
                                           const bf16* __restrict__ Bt,
                                           bf16* As, bf16* Bs,
                                           int rowBase, int colBase,
                                           f32x4 acc[2][4]) {
  const int tid = threadIdx.x;
  const int lane = tid & 63, w = tid >> 6;
  const int g = lane >> 4, r = lane & 15;

  auto stage = [&](int buf, int s) {
    {
      int c = tid;  // 64 rows x 4 chunks = 256
      int row = c >> 2, gr = c & 3, sg = gr ^ (row & 3);
      asy16(A + (size_t)(rowBase + row) * 512 + s * 32 + sg * 8,
            As + buf * 2048 + c * 8);
    }
#pragma unroll
    for (int p = 0; p < 2; ++p) {
      int c = p * 256 + tid;  // 128 rows x 4 chunks = 512
      int row = c >> 2, gr = c & 3, sg = gr ^ (row & 3);
      asy16(Bt + (size_t)(colBase + row) * 512 + s * 32 + sg * 8,
            Bs + buf * 4096 + c * 8);
    }
  };

  stage(0, 0);
  int buf = 0;
  const int rbl = (w >> 1) * 32, cbl = (w & 1) * 64;
  for (int s = 0; s < 16; ++s) {
    __syncthreads();
    if (s < 15) stage(buf ^ 1, s + 1);
    const bf16* a0 = As + buf * 2048;
    const bf16* b0 = Bs + buf * 4096;
    short8 af[2], bfr[4];
#pragma unroll
    for (int mt = 0; mt < 2; ++mt) {
      int row = rbl + mt * 16 + r;
      af[mt] = load8(a0 + (row * 4 + (g ^ (row & 3))) * 8);
    }
#pragma unroll
    for (int nt = 0; nt < 4; ++nt) {
      int col = cbl + nt * 16 + r;
      bfr[nt] = load8(b0 + (col * 4 + (g ^ (col & 3))) * 8);
    }
#pragma unroll
    for (int mt = 0; mt < 2; ++mt)
#pragma unroll
      for (int nt = 0; nt < 4; ++nt)
        acc[mt][nt] = __builtin_amdgcn_mfma_f32_16x16x32_bf16(
            af[mt], bfr[nt], acc[mt][nt], 0, 0, 0);
    buf ^= 1;
  }
}

// Fused QKV projection. Q -> [bh][n][64]; K -> Kperm; V -> Vperm.
// XCD-chunked swizzle (measured neutral in r7; kept).
__global__ __launch_bounds__(256, 3) void k_proj_qkv(
    const bf16* __restrict__ Xb, const bf16* __restrict__ Wcat,
    bf16* __restrict__ Qb, bf16* __restrict__ Kp, bf16* __restrict__ Vp) {
  const int bid = blockIdx.x;
  const int xcd = bid & 7, idx = bid >> 3;            // idx in [0,96)
  const int rowPanel = (xcd << 3) | (idx & 7);        // [0,64)
  const int colPanel = idx >> 3;                      // [0,12)
  int rowBase = rowPanel * 128, colBase = colPanel * 128;
  __shared__ __align__(16) bf16 As[2 * 4096];
  __shared__ __align__(16) bf16 Bs[2 * 4096];
  f32x4 acc[4][4] = {};
  gemm128(Xb, Wcat, As, Bs, rowBase, colBase, acc);
  const int lane = threadIdx.x & 63, w = threadIdx.x >> 6;
  const int g = lane >> 4, r = lane & 15;
#pragma unroll
  for (int mt = 0; mt < 4; ++mt) {
    int row0 = rowBase + (w >> 1) * 64 + mt * 16 + 4 * g;
    int b = row0 >> 11, n0 = row0 & 2047;
    int kt = n0 >> 6;
#pragma unroll
    for (int nt = 0; nt < 4; ++nt) {
      int col = colBase + (w & 1) * 64 + nt * 16 + r;
      if (col < 512) {
        int hh = col >> 6, dk = col & 63;
        bf16* p0 = Qb + ((size_t)(b * 8 + hh) * 2048 + n0) * 64 + dk;
#pragma unroll
        for (int rr = 0; rr < 4; ++rr)
          p0[rr * 64] = __float2bfloat16(acc[mt][nt][rr]);
      } else if (col < 1024) {
        int hh = (col >> 6) & 7, dk = col & 63;
        int half = dk >> 5, gk = (dk >> 3) & 3, jj = dk & 7;
        int kr = n0 & 63;
        int kc = kr >> 4, r0 = kr & 15;
        bf16* base = Kp + (size_t)(b * 8 + hh) * 131072 + (size_t)kt * 4096 +
                     ((kc * 2 + half) * 4 + gk) * 128 + jj;
#pragma unroll
        for (int rr = 0; rr < 4; ++rr)
          base[(r0 + rr) * 8] = __float2bfloat16(acc[mt][nt][rr]);
      } else {
        int hdv = col - 1024;
        int hh = hdv >> 6, dv = hdv & 63;
        int dvs = dv >> 4, rv = dv & 15;
        int kcol0 = n0 & 63;
        int half = kcol0 >> 5, gv = (kcol0 >> 2) & 3;
        int j0 = ((kcol0 >> 4) & 1) * 4;
        short4b pkv;
#pragma unroll
        for (int rr = 0; rr < 4; ++rr) pkv[rr] = f2b(acc[mt][nt][rr]);
        *reinterpret_cast<short4b*>(
            Vp + (size_t)(b * 8 + hh) * 131072 + (size_t)kt * 4096 +
            (((half * 4 + dvs) * 4 + gv) * 16 + rv) * 8 + j0) = pkv;
      }
    }
  }
}

// Output projection: 64x128 tiles, flat grid 512 = 2 blocks/CU, XCD swizzle.
__global__ __launch_bounds__(256, 4) void k_proj_out(
    const bf16* __restrict__ O, const bf16* __restrict__ Wot,
    float* __restrict__ out) {
  const int bid = blockIdx.x;
  const int xcd = bid & 7, idx = bid >> 3;            // idx in [0,64)
  const int rowPanel = (xcd << 4) | (idx & 15);       // [0,128)
  const int colPanel = idx >> 4;                      // [0,4)
  int rowBase = rowPanel * 64, colBase = colPanel * 128;
  __shared__ __align__(16) bf16 As[2 * 2048];
  __shared__ __align__(16) bf16 Bs[2 * 4096];
  f32x4 acc[2][4] = {};
  gemm64x128(O, Wot, As, Bs, rowBase, colBase, acc);
  const int lane = threadIdx.x & 63, w = threadIdx.x >> 6;
  const int g = lane >> 4, r = lane & 15;
#pragma unroll
  for (int mt = 0; mt < 2; ++mt) {
    int row0 = rowBase + (w >> 1) * 32 + mt * 16 + 4 * g;
#pragma unroll
    for (int nt = 0; nt < 4; ++nt) {
      int col = colBase + (w & 1) * 64 + nt * 16 + r;
#pragma unroll
      for (int rr = 0; rr < 4; ++rr)
        out[(size_t)(row0 + rr) * 512 + col] = acc[mt][nt][rr];
    }
  }
}

// ---------------- flash attention, fragment-order LDS ----------------
// grid 512 (XCD-swizzled bh x 16 qt-tiles of 128 rows), 512 thr = 8 waves,
// 16 q-rows/wave. Round-4 schedule with two VALU cuts:
//  (1) keep-bit masking: Mbits inverted in prep; per element sbfe+and
//      (2 VALU) replaces bfe+cmp+cndmask (3).
//  (2) 6x-unrolled parity macro (period-3 buffers x period-2 st/mask)
//      removes the per-iter st_cur/mw register copies. NO setprio (m190:
//      harmful on barrier-lockstep waves; r3 confirmed).
// Triple-buffered LDS, linear copy of fragment-order K/V tiles (all frag
// reads contiguous ds_read_b128, zero conflicts). QK(kt+1) before
// softmax(kt); max-free exp2 softmax; l via MFMA row-sum; hardware cvt_pk
// P-pack; shuffle-free epilogue.
__global__ __launch_bounds__(512, 4) void k_attn(const bf16* __restrict__ Q,
    const bf16* __restrict__ K, const bf16* __restrict__ V,
    const unsigned long long* __restrict__ MB, bf16* __restrict__ O) {
  const int blin = blockIdx.x;
  const int j = blin >> 3;
  const int bh = (blin & 7) * 4 + (j >> 4);
  const int qt = j & 15;
  const int b = bh >> 3, h = bh & 7;
  const int tid = threadIdx.x;
  const int lane = tid & 63;
  const int wave = tid >> 6;  // 0..7
  const int g = lane >> 4, r = lane & 15;
  const int qbase = qt * 128 + wave * 16;

  __shared__ __align__(16) bf16 Kl[3][4096];
  __shared__ __align__(16) bf16 Vl[3][4096];

  const bf16* Kp = K + (size_t)bh * 131072;
  const bf16* Vp = V + (size_t)bh * 131072;

  short8 qf0, qf1;
  {
    const bf16* Qp = Q + ((size_t)bh * 2048 + qbase + r) * 64;
    qf0 = load8(Qp + g * 8);
    qf1 = load8(Qp + 32 + g * 8);
  }
  const unsigned long long* Mp = MB + ((size_t)b * 2048 + qbase + r) * 32;

  short8 ones;
#pragma unroll
  for (int i = 0; i < 8; ++i) ones[i] = (short)0x3F80;  // bf16 1.0

  f32x4 acc[4] = {};
  f32x4 acc_l = {};

  auto stage = [&](int buf, int kt) {
    const bf16* Kg = Kp + (size_t)kt * 4096;
    const bf16* Vg = Vp + (size_t)kt * 4096;
    asy16(Kg + tid * 8, &Kl[buf][0] + tid * 8);
    asy16(Vg + tid * 8, &Vl[buf][0] + tid * 8);
  };

  auto qk = [&](const bf16* kl, f32x4 stl[4]) {
#pragma unroll
    for (int kc = 0; kc < 4; ++kc) {
      short8 kf0 = load8(kl + ((kc * 2 + 0) * 4 + g) * 128 + r * 8);
      short8 kf1 = load8(kl + ((kc * 2 + 1) * 4 + g) * 128 + r * 8);
      f32x4 z = {};
      z = __builtin_amdgcn_mfma_f32_16x16x32_bf16(kf0, qf0, z, 0, 0, 0);
      stl[kc] = __builtin_amdgcn_mfma_f32_16x16x32_bf16(kf1, qf1, z, 0, 0, 0);
    }
  };

  stage(0, 0);
  stage(1, 1);
  unsigned long long mw0, mw1;
  mw0 = Mp[0];
  __syncthreads();
  f32x4 st0[4], st1[4];
  qk(&Kl[0][0], st0);

  // One iteration. CUR/NXT/STG: buffer indices (period 3). SC/SN, MC/MN:
  // st / mask ping-pong (period 2). All compile-time after 6x unroll.
#define ATTN_ITER(KT, CUR, NXT, STG, SC, SN, MC, MN, DO_STAGE, DO_NEXT)       \
  do {                                                                        \
    __syncthreads();                                                          \
    if (DO_STAGE) stage(STG, (KT) + 2);                                       \
    if (DO_NEXT) MN = Mp[(KT) + 1];                                           \
    if (DO_NEXT) qk(&Kl[NXT][0], SN);                                         \
    unsigned ml = (unsigned)MC >> (4 * g);                                    \
    unsigned mh = (unsigned)(MC >> 32) >> (4 * g);                            \
    float p[16];                                                              \
    _Pragma("unroll") for (int kc = 0; kc < 4; ++kc)                          \
        _Pragma("unroll") for (int rr = 0; rr < 4; ++rr)                      \
      p[kc * 4 + rr] = keepmul(EXP2(SC[kc][rr]), (kc & 2) ? mh : ml,          \
                               ((kc & 1) << 4) + rr);                         \
    u32x4 q0, q1;                                                             \
    _Pragma("unroll") for (int i2 = 0; i2 < 4; ++i2) {                        \
      q0[i2] = cvtpk(p[2 * i2], p[2 * i2 + 1]);                               \
      q1[i2] = cvtpk(p[8 + 2 * i2], p[8 + 2 * i2 + 1]);                       \
    }                                                                         \
    short8 pa0 = __builtin_bit_cast(short8, q0);                              \
    short8 pa1 = __builtin_bit_cast(short8, q1);                              \
    acc_l = __builtin_amdgcn_mfma_f32_16x16x32_bf16(pa0, ones, acc_l, 0, 0, 0); \
    acc_l = __builtin_amdgcn_mfma_f32_16x16x32_bf16(pa1, ones, acc_l, 0, 0, 0); \
    const bf16* vl = &Vl[CUR][0];                                             \
    _Pragma("unroll") for (int dvs = 0; dvs < 4; ++dvs) {                     \
      short8 vb0 = load8(vl + ((0 * 4 + dvs) * 4 + g) * 128 + r * 8);         \
      short8 vb1 = load8(vl + ((1 * 4 + dvs) * 4 + g) * 128 + r * 8);         \
      acc[dvs] = __builtin_amdgcn_mfma_f32_16x16x32_bf16(pa0, vb0, acc[dvs], 0, 0, 0); \
      acc[dvs] = __builtin_amdgcn_mfma_f32_16x16x32_bf16(pa1, vb1, acc[dvs], 0, 0, 0); \
    }                                                                         \
  } while (0)

  for (int t = 0; t < 5; ++t) {
    const int kt = 6 * t;
    ATTN_ITER(kt + 0, 0, 1, 2, st0, st1, mw0, mw1, true, true);
    ATTN_ITER(kt + 1, 1, 2, 0, st1, st0, mw1, mw0, true, true);
    ATTN_ITER(kt + 2, 2, 0, 1, st0, st1, mw0, mw1, true, true);
    ATTN_ITER(kt + 3, 0, 1, 2, st1, st0, mw1, mw0, true, true);
    ATTN_ITER(kt + 4, 1, 2, 0, st0, st1, mw0, mw1, true, true);
    ATTN_ITER(kt + 5, 2, 0, 1, st1, st0, mw1, mw0, true, true);
  }
  // kt = 30, 31 tail (no stage past tile 31; no next-qk at 31)
  ATTN_ITER(30, 0, 1, 2, st0, st1, mw0, mw1, false, true);
  ATTN_ITER(31, 1, 2, 0, st1, st0, mw1, mw0, false, false);
#undef ATTN_ITER

  // shuffle-free epilogue
  float inv[4];
#pragma unroll
  for (int rr = 0; rr < 4; ++rr)
    inv[rr] = (acc_l[rr] > 0.f) ? 1.f / acc_l[rr] : 0.f;
  bf16* Op = O + ((size_t)b * 2048 + qbase + 4 * g) * 512 + h * 64;
#pragma unroll
  for (int dvs = 0; dvs < 4; ++dvs)
#pragma unroll
    for (int rr = 0; rr < 4; ++rr)
      Op[rr * 512 + dvs * 16 + r] = __float2bfloat16(acc[dvs][rr] * inv[rr]);
}

// ---------------- launch ----------------

extern "C" void kernel_launch(void* const* d_in, const int* in_sizes, int n_in,
                              void* d_out, int out_size, void* d_ws, size_t ws_size,
                              hipStream_t stream) {
  const float* q    = (const float*)d_in[0];
  const int*   mask = (const int*)d_in[1];
  const float* Wq   = (const float*)d_in[2];
  const float* Wk   = (const float*)d_in[3];
  const float* Wv   = (const float*)d_in[4];
  const float* Wo   = (const float*)d_in[5];
  float* out = (float*)d_out;

  char* ws = (char*)d_ws;
  const size_t MB1 = 1024 * 1024;
  // Ob aliases Xb: Xb is dead after k_proj_qkv, Ob is written by k_attn.
  bf16* Xb   = (bf16*)(ws + 0);          // 8 MB [8192][512]
  bf16* Ob   = (bf16*)(ws + 0);          // 8 MB [bn][512] (alias of Xb)
  bf16* Qb   = (bf16*)(ws + 8 * MB1);    // 8 MB [bh][n][64]
  bf16* Kpm  = (bf16*)(ws + 16 * MB1);   // 8 MB fragment-order K
  bf16* Vpm  = (bf16*)(ws + 24 * MB1);   // 8 MB fragment-order V
  unsigned long long* Mbits = (unsigned long long*)(ws + 32 * MB1);  // 2 MB
  bf16* Wcat = (bf16*)(ws + 34 * MB1);   // 1.5 MB
  bf16* Wot  = (bf16*)(ws + 34 * MB1 + 1536 * 512 * 2);  // 0.5 MB

  k_prep<<<20736, 256, 0, stream>>>((const float4*)q, (ushort4*)Xb,
                                    Wq, Wk, Wv, Wo, Wcat, Wot,
                                    (const int4*)mask, Mbits);
  k_proj_qkv<<<768, 256, 0, stream>>>(Xb, Wcat, Qb, Kpm, Vpm);
  k_attn<<<512, 512, 0, stream>>>(Qb, Kpm, Vpm, Mbits, Ob);
  k_proj_out<<<512, 256, 0, stream>>>(Ob, Wot, out);
}

// Round 9
// 199.947 us; speedup vs baseline: 1.0024x; 1.0024x over previous
//
#include <hip/hip_runtime.h>
#include <hip/hip_bf16.h>
#include <stdint.h>

using bf16 = __hip_bfloat16;
typedef __attribute__((ext_vector_type(8))) short short8;
typedef __attribute__((ext_vector_type(4))) short short4b;
typedef __attribute__((ext_vector_type(4))) float f32x4;
typedef __attribute__((ext_vector_type(4))) unsigned int u32x4;

#if __has_builtin(__builtin_amdgcn_exp2f)
#define EXP2(x) __builtin_amdgcn_exp2f(x)
#else
#define EXP2(x) exp2f(x)
#endif

__device__ __forceinline__ short8 load8(const bf16* p) {
  return *reinterpret_cast<const short8*>(p);
}
__device__ __forceinline__ short f2b(float f) {
  return __builtin_bit_cast(short, __float2bfloat16(f));
}
// hardware packed f32->bf16 pair conversion (lo -> low 16b). Only used for
// the attention P tile: values in [0,1], and the same rounding feeds both
// the PV numerator and the l-sum denominator, so the mode change cancels.
__device__ __forceinline__ unsigned int cvtpk(float lo, float hi) {
  unsigned int r;
  asm("v_cvt_pk_bf16_f32 %0, %1, %2" : "=v"(r) : "v"(lo), "v"(hi));
  return r;
}
// Masked-keep multiply: Mbits stores KEEP bits (inverted mask). One sbfe
// (sign-extend the keep bit to 0 / 0xFFFFFFFF) + one AND = 2 VALU per
// element, vs bfe+cmp+cndmask (3) for the ternary form.
__device__ __forceinline__ float keepmul(float e, unsigned w, int pos) {
#if __has_builtin(__builtin_amdgcn_sbfe)
  unsigned km = (unsigned)__builtin_amdgcn_sbfe((int)w, pos, 1);
  return __builtin_bit_cast(float, __builtin_bit_cast(unsigned, e) & km);
#else
  return ((w >> pos) & 1u) ? e : 0.f;  // keep-bit semantics
#endif
}
__device__ __forceinline__ void asy16(const bf16* g, bf16* l) {
  __builtin_amdgcn_global_load_lds(
      (const __attribute__((address_space(1))) void*)g,
      (__attribute__((address_space(3))) void*)l, 16, 0, 0);
}

// K fragment-order layout (per bh, per kt tile of 64 keys):
//   Kperm[((kc*2+half)*4+g)*128 + r*8 + j] = K[key=kc*16+r][d=half*32+8g+j]
// V fragment-order layout (PV contraction permuted by pi):
//   Vperm[((half*4+dvs)*4+g)*128 + r*8 + j] = V[dv=dvs*16+r][k=half*32+pi(g,j)]
//   pi(g,j) = (j>>2)*16 + 4g + (j&3)
// Both are 4096 elements per (bh,kt); staging to LDS is a linear 8KB copy.
// Note: for a FIXED key row, 8 consecutive d (dk%8==0 start) are 8
// consecutive Kperm elements -> 16B chunks, exploited by the epilogue.

// ---------------- fused prep kernel ----------------
// blocks [0,4096): x f32->bf16 ; [4096,4352): LDS-tiled weight transpose ;
// [4352,20736): mask bit-pack (stored INVERTED: bit=1 means keep).
__global__ void k_prep(const float4* __restrict__ x, ushort4* __restrict__ xb,
                       const float* __restrict__ Wq, const float* __restrict__ Wk,
                       const float* __restrict__ Wv, const float* __restrict__ Wo,
                       bf16* __restrict__ Wcat, bf16* __restrict__ Wot,
                       const int4* __restrict__ m4,
                       unsigned long long* __restrict__ bits) {
  int blk = blockIdx.x;
  const int tid = threadIdx.x;
  if (blk < 4096) {
    int i = blk * 256 + tid;
    float4 v = x[i];
    ushort4 o;
    o.x = (unsigned short)f2b(v.x);
    o.y = (unsigned short)f2b(v.y);
    o.z = (unsigned short)f2b(v.z);
    o.w = (unsigned short)f2b(v.w);
    xb[i] = o;
  } else if (blk < 4352) {
    int t = blk - 4096;
    __shared__ float T[64][65];
    if (t < 192) {
      // W{q,k,v}[h][512][64] -> Wcat[(which*512+h*64+dk)][d], 64x64 d-tiles
      int which = t >> 6;
      int h = (t >> 3) & 7, dt = t & 7;
      const float* W = (which == 0) ? Wq : ((which == 1) ? Wk : Wv);
#pragma unroll
      for (int p = 0; p < 4; ++p) {
        int row = p * 16 + (tid >> 4);
        float4 v = *(const float4*)(W + (size_t)(h * 512 + dt * 64 + row) * 64 +
                                    (tid & 15) * 4);
        T[row][(tid & 15) * 4 + 0] = v.x;
        T[row][(tid & 15) * 4 + 1] = v.y;
        T[row][(tid & 15) * 4 + 2] = v.z;
        T[row][(tid & 15) * 4 + 3] = v.w;
      }
      __syncthreads();
      float scale = (which == 0) ? 0.18033688011112042f : 1.0f;  // 0.125*log2e
      int jj = tid >> 2, i0 = (tid & 3) * 16;
#pragma unroll
      for (int q = 0; q < 2; ++q) {
        short8 o;
#pragma unroll
        for (int e = 0; e < 8; ++e) o[e] = f2b(T[i0 + q * 8 + e][jj] * scale);
        *(short8*)(Wcat + (size_t)(which * 512 + h * 64 + jj) * 512 + dt * 64 +
                   i0 + q * 8) = o;
      }
    } else {
      // Wo[h][64][512] -> Wot[e][h*64+v], 64x64 e-tiles
      int t2 = t - 192;
      int h = t2 >> 3, et = t2 & 7;
#pragma unroll
      for (int p = 0; p < 4; ++p) {
        int row = p * 16 + (tid >> 4);
        float4 v = *(const float4*)(Wo + (size_t)(h * 64 + row) * 512 + et * 64 +
                                    (tid & 15) * 4);
        T[row][(tid & 15) * 4 + 0] = v.x;
        T[row][(tid & 15) * 4 + 1] = v.y;
        T[row][(tid & 15) * 4 + 2] = v.z;
        T[row][(tid & 15) * 4 + 3] = v.w;
      }
      __syncthreads();
      int jj = tid >> 2, i0 = (tid & 3) * 16;
#pragma unroll
      for (int q = 0; q < 2; ++q) {
        short8 o;
#pragma unroll
        for (int e = 0; e < 8; ++e) o[e] = f2b(T[i0 + q * 8 + e][jj]);
        *(short8*)(Wot + (size_t)(et * 64 + jj) * 512 + h * 64 + i0 + q * 8) = o;
      }
    }
  } else {
    int i = (blk - 4352) * 256 + tid;
    int4 v = m4[i];
    unsigned int nib = (unsigned)(v.x != 0) | ((unsigned)(v.y != 0) << 1) |
                       ((unsigned)(v.z != 0) << 2) | ((unsigned)(v.w != 0) << 3);
    unsigned long long w = (unsigned long long)nib << (4 * (tid & 15));
    w |= __shfl_xor(w, 1);
    w |= __shfl_xor(w, 2);
    w |= __shfl_xor(w, 4);
    w |= __shfl_xor(w, 8);
    if ((tid & 15) == 0) bits[i >> 4] = ~w;  // inverted: 1 = keep
  }
}

// ---------------- 128x128 GEMM core, BK=32 double-buffered ----------------
__device__ __forceinline__ void gemm128(const bf16* __restrict__ A,
                                        const bf16* __restrict__ Bt,
                                        bf16* As, bf16* Bs,
                                        int rowBase, int colBase,
                                        f32x4 acc[4][4]) {
  const int tid = threadIdx.x;
  const int lane = tid & 63, w = tid >> 6;
  const int g = lane >> 4, r = lane & 15;

  auto stage = [&](int buf, int s) {
#pragma unroll
    for (int p = 0; p < 2; ++p) {
      int c = p * 256 + tid;
      int row = c >> 2, gr = c & 3, sg = gr ^ (row & 3);
      asy16(A + (size_t)(rowBase + row) * 512 + s * 32 + sg * 8,
            As + buf * 4096 + c * 8);
    }
#pragma unroll
    for (int p = 0; p < 2; ++p) {
      int c = p * 256 + tid;
      int row = c >> 2, gr = c & 3, sg = gr ^ (row & 3);
      asy16(Bt + (size_t)(colBase + row) * 512 + s * 32 + sg * 8,
            Bs + buf * 4096 + c * 8);
    }
  };

  stage(0, 0);
  int buf = 0;
  const int rbl = (w >> 1) * 64, cbl = (w & 1) * 64;
  for (int s = 0; s < 16; ++s) {
    __syncthreads();
    if (s < 15) stage(buf ^ 1, s + 1);
    const bf16* a0 = As + buf * 4096;
    const bf16* b0 = Bs + buf * 4096;
    short8 af[4], bfr[4];
#pragma unroll
    for (int mt = 0; mt < 4; ++mt) {
      int row = rbl + mt * 16 + r;
      af[mt] = load8(a0 + (row * 4 + (g ^ (row & 3))) * 8);
    }
#pragma unroll
    for (int nt = 0; nt < 4; ++nt) {
      int col = cbl + nt * 16 + r;
      bfr[nt] = load8(b0 + (col * 4 + (g ^ (col & 3))) * 8);
    }
#pragma unroll
    for (int mt = 0; mt < 4; ++mt)
#pragma unroll
      for (int nt = 0; nt < 4; ++nt)
        acc[mt][nt] = __builtin_amdgcn_mfma_f32_16x16x32_bf16(
            af[mt], bfr[nt], acc[mt][nt], 0, 0, 0);
    buf ^= 1;
  }
}

// ---------------- 64x128 GEMM core (for k_proj_out), BK=32 dbuf ----------
__device__ __forceinline__ void gemm64x128(const bf16* __restrict__ A,
                                           const bf16* __restrict__ Bt,
                                           bf16* As, bf16* Bs,
                                           int rowBase, int colBase,
                                           f32x4 acc[2][4]) {
  const int tid = threadIdx.x;
  const int lane = tid & 63, w = tid >> 6;
  const int g = lane >> 4, r = lane & 15;

  auto stage = [&](int buf, int s) {
    {
      int c = tid;  // 64 rows x 4 chunks = 256
      int row = c >> 2, gr = c & 3, sg = gr ^ (row & 3);
      asy16(A + (size_t)(rowBase + row) * 512 + s * 32 + sg * 8,
            As + buf * 2048 + c * 8);
    }
#pragma unroll
    for (int p = 0; p < 2; ++p) {
      int c = p * 256 + tid;  // 128 rows x 4 chunks = 512
      int row = c >> 2, gr = c & 3, sg = gr ^ (row & 3);
      asy16(Bt + (size_t)(colBase + row) * 512 + s * 32 + sg * 8,
            Bs + buf * 4096 + c * 8);
    }
  };

  stage(0, 0);
  int buf = 0;
  const int rbl = (w >> 1) * 32, cbl = (w & 1) * 64;
  for (int s = 0; s < 16; ++s) {
    __syncthreads();
    if (s < 15) stage(buf ^ 1, s + 1);
    const bf16* a0 = As + buf * 2048;
    const bf16* b0 = Bs + buf * 4096;
    short8 af[2], bfr[4];
#pragma unroll
    for (int mt = 0; mt < 2; ++mt) {
      int row = rbl + mt * 16 + r;
      af[mt] = load8(a0 + (row * 4 + (g ^ (row & 3))) * 8);
    }
#pragma unroll
    for (int nt = 0; nt < 4; ++nt) {
      int col = cbl + nt * 16 + r;
      bfr[nt] = load8(b0 + (col * 4 + (g ^ (col & 3))) * 8);
    }
#pragma unroll
    for (int mt = 0; mt < 2; ++mt)
#pragma unroll
      for (int nt = 0; nt < 4; ++nt)
        acc[mt][nt] = __builtin_amdgcn_mfma_f32_16x16x32_bf16(
            af[mt], bfr[nt], acc[mt][nt], 0, 0, 0);
    buf ^= 1;
  }
}

// Fused QKV projection. Q -> [bh][n][64]; K -> Kperm; V -> Vperm.
// XCD-chunked swizzle (measured neutral in r7; kept).
// NEW (r9): Q- and K-panel blocks stage the 128x128 output tile through
// LDS (4 stripe passes of 32x128, reusing the dead As buffer) and flush
// with 16B coalesced stores — VMEM stores per thread drop 64 -> 8
// (the old path was 64 scalar 2B scattered stores). V-panel blocks keep
// the short4b path (already 8B stores). The branch is block-uniform.
__global__ __launch_bounds__(256, 3) void k_proj_qkv(
    const bf16* __restrict__ Xb, const bf16* __restrict__ Wcat,
    bf16* __restrict__ Qb, bf16* __restrict__ Kp, bf16* __restrict__ Vp) {
  const int bid = blockIdx.x;
  const int xcd = bid & 7, idx = bid >> 3;            // idx in [0,96)
  const int rowPanel = (xcd << 3) | (idx & 7);        // [0,64)
  const int colPanel = idx >> 3;                      // [0,12)
  int rowBase = rowPanel * 128, colBase = colPanel * 128;
  __shared__ __align__(16) bf16 As[2 * 4096];
  __shared__ __align__(16) bf16 Bs[2 * 4096];
  f32x4 acc[4][4] = {};
  gemm128(Xb, Wcat, As, Bs, rowBase, colBase, acc);
  const int tid = threadIdx.x;
  const int lane = tid & 63, w = tid >> 6;
  const int g = lane >> 4, r = lane & 15;

  if (colPanel < 8) {
    // ---- LDS-coalesced epilogue (Q panels 0-3, K panels 4-7) ----
    // Tl stripe: 32 rows x 128 cols, padded stride 136 (16B-aligned rows,
    // breaks the 4-row bank alias on the scatter writes). 32*136*2B = 8.5KB
    // fits in As (16KB, dead after the loop's final barrier-gated reads).
    bf16* Tl = As;
    const int LD = 136;
#pragma unroll
    for (int p = 0; p < 4; ++p) {
      __syncthreads();  // pass p-1 flush done / gemm reads done (p==0)
      if ((w >> 1) == (p >> 1)) {
#pragma unroll
        for (int mi = 0; mi < 2; ++mi) {
          int mt = 2 * (p & 1) + mi;
          int srow0 = mi * 16 + 4 * g;  // stripe-rel row of acc[mt][*][0]
#pragma unroll
          for (int nt = 0; nt < 4; ++nt) {
            int colRel = (w & 1) * 64 + nt * 16 + r;
#pragma unroll
            for (int rr = 0; rr < 4; ++rr)
              Tl[(srow0 + rr) * LD + colRel] =
                  __float2bfloat16(acc[mt][nt][rr]);
          }
        }
      }
      __syncthreads();
      // flush stripe p: 256 threads x 2 chunks x 16B
      int srow = tid >> 3;
      int c0 = (tid & 7) * 16;  // element col of first chunk
      int nAbs = rowBase + 32 * p + srow;
      int b = nAbs >> 11, n0 = nAbs & 2047;
#pragma unroll
      for (int q2 = 0; q2 < 2; ++q2) {
        int colRel = c0 + 8 * q2;
        short8 v = *reinterpret_cast<const short8*>(Tl + srow * LD + colRel);
        int col = colBase + colRel;
        if (colPanel < 4) {
          int hh = col >> 6, dk = col & 63;
          *reinterpret_cast<short8*>(
              Qb + ((size_t)(b * 8 + hh) * 2048 + n0) * 64 + dk) = v;
        } else {
          int hh = (col >> 6) & 7, dk = col & 63;
          int half = dk >> 5, gk = (dk >> 3) & 3;  // dk%8 == 0
          int kt = n0 >> 6, kr = n0 & 63;
          int kc = kr >> 4, r0 = kr & 15;
          *reinterpret_cast<short8*>(
              Kp + (size_t)(b * 8 + hh) * 131072 + (size_t)kt * 4096 +
              ((kc * 2 + half) * 4 + gk) * 128 + r0 * 8) = v;
        }
      }
    }
  } else {
    // ---- V panels: original short4b scatter (8B stores) ----
#pragma unroll
    for (int mt = 0; mt < 4; ++mt) {
      int row0 = rowBase + (w >> 1) * 64 + mt * 16 + 4 * g;
      int b = row0 >> 11, n0 = row0 & 2047;
      int kt = n0 >> 6;
#pragma unroll
      for (int nt = 0; nt < 4; ++nt) {
        int col = colBase + (w & 1) * 64 + nt * 16 + r;
        int hdv = col - 1024;
        int hh = hdv >> 6, dv = hdv & 63;
        int dvs = dv >> 4, rv = dv & 15;
        int kcol0 = n0 & 63;
        int half = kcol0 >> 5, gv = (kcol0 >> 2) & 3;
        int j0 = ((kcol0 >> 4) & 1) * 4;
        short4b pkv;
#pragma unroll
        for (int rr = 0; rr < 4; ++rr) pkv[rr] = f2b(acc[mt][nt][rr]);
        *reinterpret_cast<short4b*>(
            Vp + (size_t)(b * 8 + hh) * 131072 + (size_t)kt * 4096 +
            (((half * 4 + dvs) * 4 + gv) * 16 + rv) * 8 + j0) = pkv;
      }
    }
  }
}

// Output projection: 64x128 tiles, flat grid 512 = 2 blocks/CU, XCD swizzle.
__global__ __launch_bounds__(256, 4) void k_proj_out(
    const bf16* __restrict__ O, const bf16* __restrict__ Wot,
    float* __restrict__ out) {
  const int bid = blockIdx.x;
  const int xcd = bid & 7, idx = bid >> 3;            // idx in [0,64)
  const int rowPanel = (xcd << 4) | (idx & 15);       // [0,128)
  const int colPanel = idx >> 4;                      // [0,4)
  int rowBase = rowPanel * 64, colBase = colPanel * 128;
  __shared__ __align__(16) bf16 As[2 * 2048];
  __shared__ __align__(16) bf16 Bs[2 * 4096];
  f32x4 acc[2][4] = {};
  gemm64x128(O, Wot, As, Bs, rowBase, colBase, acc);
  const int lane = threadIdx.x & 63, w = threadIdx.x >> 6;
  const int g = lane >> 4, r = lane & 15;
#pragma unroll
  for (int mt = 0; mt < 2; ++mt) {
    int row0 = rowBase + (w >> 1) * 32 + mt * 16 + 4 * g;
#pragma unroll
    for (int nt = 0; nt < 4; ++nt) {
      int col = colBase + (w & 1) * 64 + nt * 16 + r;
#pragma unroll
      for (int rr = 0; rr < 4; ++rr)
        out[(size_t)(row0 + rr) * 512 + col] = acc[mt][nt][rr];
    }
  }
}

// ---------------- flash attention, fragment-order LDS ----------------
// grid 512 (XCD-swizzled bh x 16 qt-tiles of 128 rows), 512 thr = 8 waves,
// 16 q-rows/wave. r8 configuration (measured best, 53.8us):
//  - keep-bit masking (sbfe+and, 2 VALU/elem)
//  - 6x-unrolled parity macro (no register copies), NO setprio
//  - hardware cvt_pk P-pack; max-free exp2 softmax; l via MFMA row-sum
// Triple-buffered LDS, linear copy of fragment-order K/V tiles (all frag
// reads contiguous ds_read_b128, zero conflicts). QK(kt+1) before
// softmax(kt); shuffle-free epilogue.
__global__ __launch_bounds__(512, 4) void k_attn(const bf16* __restrict__ Q,
    const bf16* __restrict__ K, const bf16* __restrict__ V,
    const unsigned long long* __restrict__ MB, bf16* __restrict__ O) {
  const int blin = blockIdx.x;
  const int j = blin >> 3;
  const int bh = (blin & 7) * 4 + (j >> 4);
  const int qt = j & 15;
  const int b = bh >> 3, h = bh & 7;
  const int tid = threadIdx.x;
  const int lane = tid & 63;
  const int wave = tid >> 6;  // 0..7
  const int g = lane >> 4, r = lane & 15;
  const int qbase = qt * 128 + wave * 16;

  __shared__ __align__(16) bf16 Kl[3][4096];
  __shared__ __align__(16) bf16 Vl[3][4096];

  const bf16* Kp = K + (size_t)bh * 131072;
  const bf16* Vp = V + (size_t)bh * 131072;

  short8 qf0, qf1;
  {
    const bf16* Qp = Q + ((size_t)bh * 2048 + qbase + r) * 64;
    qf0 = load8(Qp + g * 8);
    qf1 = load8(Qp + 32 + g * 8);
  }
  const unsigned long long* Mp = MB + ((size_t)b * 2048 + qbase + r) * 32;

  short8 ones;
#pragma unroll
  for (int i = 0; i < 8; ++i) ones[i] = (short)0x3F80;  // bf16 1.0

  f32x4 acc[4] = {};
  f32x4 acc_l = {};

  auto stage = [&](int buf, int kt) {
    const bf16* Kg = Kp + (size_t)kt * 4096;
    const bf16* Vg = Vp + (size_t)kt * 4096;
    asy16(Kg + tid * 8, &Kl[buf][0] + tid * 8);
    asy16(Vg + tid * 8, &Vl[buf][0] + tid * 8);
  };

  auto qk = [&](const bf16* kl, f32x4 stl[4]) {
#pragma unroll
    for (int kc = 0; kc < 4; ++kc) {
      short8 kf0 = load8(kl + ((kc * 2 + 0) * 4 + g) * 128 + r * 8);
      short8 kf1 = load8(kl + ((kc * 2 + 1) * 4 + g) * 128 + r * 8);
      f32x4 z = {};
      z = __builtin_amdgcn_mfma_f32_16x16x32_bf16(kf0, qf0, z, 0, 0, 0);
      stl[kc] = __builtin_amdgcn_mfma_f32_16x16x32_bf16(kf1, qf1, z, 0, 0, 0);
    }
  };

  stage(0, 0);
  stage(1, 1);
  unsigned long long mw0, mw1;
  mw0 = Mp[0];
  __syncthreads();
  f32x4 st0[4], st1[4];
  qk(&Kl[0][0], st0);

  // One iteration. CUR/NXT/STG: buffer indices (period 3). SC/SN, MC/MN:
  // st / mask ping-pong (period 2). All compile-time after 6x unroll.
#define ATTN_ITER(KT, CUR, NXT, STG, SC, SN, MC, MN, DO_STAGE, DO_NEXT)       \
  do {                                                                        \
    __syncthreads();                                                          \
    if (DO_STAGE) stage(STG, (KT) + 2);                                       \
    if (DO_NEXT) MN = Mp[(KT) + 1];                                           \
    if (DO_NEXT) qk(&Kl[NXT][0], SN);                                         \
    unsigned ml = (unsigned)MC >> (4 * g);                                    \
    unsigned mh = (unsigned)(MC >> 32) >> (4 * g);                            \
    float p[16];                                                              \
    _Pragma("unroll") for (int kc = 0; kc < 4; ++kc)                          \
        _Pragma("unroll") for (int rr = 0; rr < 4; ++rr)                      \
      p[kc * 4 + rr] = keepmul(EXP2(SC[kc][rr]), (kc & 2) ? mh : ml,          \
                               ((kc & 1) << 4) + rr);                         \
    u32x4 q0, q1;                                                             \
    _Pragma("unroll") for (int i2 = 0; i2 < 4; ++i2) {                        \
      q0[i2] = cvtpk(p[2 * i2], p[2 * i2 + 1]);                               \
      q1[i2] = cvtpk(p[8 + 2 * i2], p[8 + 2 * i2 + 1]);                       \
    }                                                                         \
    short8 pa0 = __builtin_bit_cast(short8, q0);                              \
    short8 pa1 = __builtin_bit_cast(short8, q1);                              \
    acc_l = __builtin_amdgcn_mfma_f32_16x16x32_bf16(pa0, ones, acc_l, 0, 0, 0); \
    acc_l = __builtin_amdgcn_mfma_f32_16x16x32_bf16(pa1, ones, acc_l, 0, 0, 0); \
    const bf16* vl = &Vl[CUR][0];                                             \
    _Pragma("unroll") for (int dvs = 0; dvs < 4; ++dvs) {                     \
      short8 vb0 = load8(vl + ((0 * 4 + dvs) * 4 + g) * 128 + r * 8);         \
      short8 vb1 = load8(vl + ((1 * 4 + dvs) * 4 + g) * 128 + r * 8);         \
      acc[dvs] = __builtin_amdgcn_mfma_f32_16x16x32_bf16(pa0, vb0, acc[dvs], 0, 0, 0); \
      acc[dvs] = __builtin_amdgcn_mfma_f32_16x16x32_bf16(pa1, vb1, acc[dvs], 0, 0, 0); \
    }                                                                         \
  } while (0)

  for (int t = 0; t < 5; ++t) {
    const int kt = 6 * t;
    ATTN_ITER(kt + 0, 0, 1, 2, st0, st1, mw0, mw1, true, true);
    ATTN_ITER(kt + 1, 1, 2, 0, st1, st0, mw1, mw0, true, true);
    ATTN_ITER(kt + 2, 2, 0, 1, st0, st1, mw0, mw1, true, true);
    ATTN_ITER(kt + 3, 0, 1, 2, st1, st0, mw1, mw0, true, true);
    ATTN_ITER(kt + 4, 1, 2, 0, st0, st1, mw0, mw1, true, true);
    ATTN_ITER(kt + 5, 2, 0, 1, st1, st0, mw1, mw0, true, true);
  }
  // kt = 30, 31 tail (no stage past tile 31; no next-qk at 31)
  ATTN_ITER(30, 0, 1, 2, st0, st1, mw0, mw1, false, true);
  ATTN_ITER(31, 1, 2, 0, st1, st0, mw1, mw0, false, false);
#undef ATTN_ITER

  // shuffle-free epilogue
  float inv[4];
#pragma unroll
  for (int rr = 0; rr < 4; ++rr)
    inv[rr] = (acc_l[rr] > 0.f) ? 1.f / acc_l[rr] : 0.f;
  bf16* Op = O + ((size_t)b * 2048 + qbase + 4 * g) * 512 + h * 64;
#pragma unroll
  for (int dvs = 0; dvs < 4; ++dvs)
#pragma unroll
    for (int rr = 0; rr < 4; ++rr)
      Op[rr * 512 + dvs * 16 + r] = __float2bfloat16(acc[dvs][rr] * inv[rr]);
}

// ---------------- launch ----------------

extern "C" void kernel_launch(void* const* d_in, const int* in_sizes, int n_in,
                              void* d_out, int out_size, void* d_ws, size_t ws_size,
                              hipStream_t stream) {
  const float* q    = (const float*)d_in[0];
  const int*   mask = (const int*)d_in[1];
  const float* Wq   = (const float*)d_in[2];
  const float* Wk   = (const float*)d_in[3];
  const float* Wv   = (const float*)d_in[4];
  const float* Wo   = (const float*)d_in[5];
  float* out = (float*)d_out;

  char* ws = (char*)d_ws;
  const size_t MB1 = 1024 * 1024;
  // Ob aliases Xb: Xb is dead after k_proj_qkv, Ob is written by k_attn.
  bf16* Xb   = (bf16*)(ws + 0);          // 8 MB [8192][512]
  bf16* Ob   = (bf16*)(ws + 0);          // 8 MB [bn][512] (alias of Xb)
  bf16* Qb   = (bf16*)(ws + 8 * MB1);    // 8 MB [bh][n][64]
  bf16* Kpm  = (bf16*)(ws + 16 * MB1);   // 8 MB fragment-order K
  bf16* Vpm  = (bf16*)(ws + 24 * MB1);   // 8 MB fragment-order V
  unsigned long long* Mbits = (unsigned long long*)(ws + 32 * MB1);  // 2 MB
  bf16* Wcat = (bf16*)(ws + 34 * MB1);   // 1.5 MB
  bf16* Wot  = (bf16*)(ws + 34 * MB1 + 1536 * 512 * 2);  // 0.5 MB

  k_prep<<<20736, 256, 0, stream>>>((const float4*)q, (ushort4*)Xb,
                                    Wq, Wk, Wv, Wo, Wcat, Wot,
                                    (const int4*)mask, Mbits);
  k_proj_qkv<<<768, 256, 0, stream>>>(Xb, Wcat, Qb, Kpm, Vpm);
  k_attn<<<512, 512, 0, stream>>>(Qb, Kpm, Vpm, Mbits, Ob);
  k_proj_out<<<512, 256, 0, stream>>>(Ob, Wot, out);
}

// Round 10
// 196.194 us; speedup vs baseline: 1.0216x; 1.0191x over previous
//
#include <hip/hip_runtime.h>
#include <hip/hip_bf16.h>
#include <stdint.h>

using bf16 = __hip_bfloat16;
typedef __attribute__((ext_vector_type(8))) short short8;
typedef __attribute__((ext_vector_type(4))) short short4b;
typedef __attribute__((ext_vector_type(4))) float f32x4;
typedef __attribute__((ext_vector_type(4))) unsigned int u32x4;

#if __has_builtin(__builtin_amdgcn_exp2f)
#define EXP2(x) __builtin_amdgcn_exp2f(x)
#else
#define EXP2(x) exp2f(x)
#endif

__device__ __forceinline__ short8 load8(const bf16* p) {
  return *reinterpret_cast<const short8*>(p);
}
__device__ __forceinline__ short f2b(float f) {
  return __builtin_bit_cast(short, __float2bfloat16(f));
}
// hardware packed f32->bf16 pair conversion (lo -> low 16b). Only used for
// the attention P tile: values in [0,1], and the same rounding feeds both
// the PV numerator and the l-sum denominator, so the mode change cancels.
__device__ __forceinline__ unsigned int cvtpk(float lo, float hi) {
  unsigned int r;
  asm("v_cvt_pk_bf16_f32 %0, %1, %2" : "=v"(r) : "v"(lo), "v"(hi));
  return r;
}
// Masked-keep multiply: Mbits stores KEEP bits (inverted mask). One sbfe
// (sign-extend the keep bit to 0 / 0xFFFFFFFF) + one AND = 2 VALU per
// element, vs bfe+cmp+cndmask (3) for the ternary form.
__device__ __forceinline__ float keepmul(float e, unsigned w, int pos) {
#if __has_builtin(__builtin_amdgcn_sbfe)
  unsigned km = (unsigned)__builtin_amdgcn_sbfe((int)w, pos, 1);
  return __builtin_bit_cast(float, __builtin_bit_cast(unsigned, e) & km);
#else
  return ((w >> pos) & 1u) ? e : 0.f;  // keep-bit semantics
#endif
}
__device__ __forceinline__ void asy16(const bf16* g, bf16* l) {
  __builtin_amdgcn_global_load_lds(
      (const __attribute__((address_space(1))) void*)g,
      (__attribute__((address_space(3))) void*)l, 16, 0, 0);
}

// K fragment-order layout (per bh, per kt tile of 64 keys):
//   Kperm[((kc*2+half)*4+g)*128 + r*8 + j] = K[key=kc*16+r][d=half*32+8g+j]
// V fragment-order layout (PV contraction permuted by pi):
//   Vperm[((half*4+dvs)*4+g)*128 + r*8 + j] = V[dv=dvs*16+r][k=half*32+pi(g,j)]
//   pi(g,j) = (j>>2)*16 + 4g + (j&3)
// Both are 4096 elements per (bh,kt); staging to LDS is a linear 8KB copy.

// ---------------- fused prep kernel (identical to r8/r9) ----------------
// blocks [0,4096): x f32->bf16 ; [4096,4352): LDS-tiled weight transpose ;
// [4352,20736): mask bit-pack (stored INVERTED: bit=1 means keep).
__global__ void k_prep(const float4* __restrict__ x, ushort4* __restrict__ xb,
                       const float* __restrict__ Wq, const float* __restrict__ Wk,
                       const float* __restrict__ Wv, const float* __restrict__ Wo,
                       bf16* __restrict__ Wcat, bf16* __restrict__ Wot,
                       const int4* __restrict__ m4,
                       unsigned long long* __restrict__ bits) {
  int blk = blockIdx.x;
  const int tid = threadIdx.x;
  if (blk < 4096) {
    int i = blk * 256 + tid;
    float4 v = x[i];
    ushort4 o;
    o.x = (unsigned short)f2b(v.x);
    o.y = (unsigned short)f2b(v.y);
    o.z = (unsigned short)f2b(v.z);
    o.w = (unsigned short)f2b(v.w);
    xb[i] = o;
  } else if (blk < 4352) {
    int t = blk - 4096;
    __shared__ float T[64][65];
    if (t < 192) {
      // W{q,k,v}[h][512][64] -> Wcat[(which*512+h*64+dk)][d], 64x64 d-tiles
      int which = t >> 6;
      int h = (t >> 3) & 7, dt = t & 7;
      const float* W = (which == 0) ? Wq : ((which == 1) ? Wk : Wv);
#pragma unroll
      for (int p = 0; p < 4; ++p) {
        int row = p * 16 + (tid >> 4);
        float4 v = *(const float4*)(W + (size_t)(h * 512 + dt * 64 + row) * 64 +
                                    (tid & 15) * 4);
        T[row][(tid & 15) * 4 + 0] = v.x;
        T[row][(tid & 15) * 4 + 1] = v.y;
        T[row][(tid & 15) * 4 + 2] = v.z;
        T[row][(tid & 15) * 4 + 3] = v.w;
      }
      __syncthreads();
      float scale = (which == 0) ? 0.18033688011112042f : 1.0f;  // 0.125*log2e
      int jj = tid >> 2, i0 = (tid & 3) * 16;
#pragma unroll
      for (int q = 0; q < 2; ++q) {
        short8 o;
#pragma unroll
        for (int e = 0; e < 8; ++e) o[e] = f2b(T[i0 + q * 8 + e][jj] * scale);
        *(short8*)(Wcat + (size_t)(which * 512 + h * 64 + jj) * 512 + dt * 64 +
                   i0 + q * 8) = o;
      }
    } else {
      // Wo[h][64][512] -> Wot[e][h*64+v], 64x64 e-tiles
      int t2 = t - 192;
      int h = t2 >> 3, et = t2 & 7;
#pragma unroll
      for (int p = 0; p < 4; ++p) {
        int row = p * 16 + (tid >> 4);
        float4 v = *(const float4*)(Wo + (size_t)(h * 64 + row) * 512 + et * 64 +
                                    (tid & 15) * 4);
        T[row][(tid & 15) * 4 + 0] = v.x;
        T[row][(tid & 15) * 4 + 1] = v.y;
        T[row][(tid & 15) * 4 + 2] = v.z;
        T[row][(tid & 15) * 4 + 3] = v.w;
      }
      __syncthreads();
      int jj = tid >> 2, i0 = (tid & 3) * 16;
#pragma unroll
      for (int q = 0; q < 2; ++q) {
        short8 o;
#pragma unroll
        for (int e = 0; e < 8; ++e) o[e] = f2b(T[i0 + q * 8 + e][jj]);
        *(short8*)(Wot + (size_t)(et * 64 + jj) * 512 + h * 64 + i0 + q * 8) = o;
      }
    }
  } else {
    int i = (blk - 4352) * 256 + tid;
    int4 v = m4[i];
    unsigned int nib = (unsigned)(v.x != 0) | ((unsigned)(v.y != 0) << 1) |
                       ((unsigned)(v.z != 0) << 2) | ((unsigned)(v.w != 0) << 3);
    unsigned long long w = (unsigned long long)nib << (4 * (tid & 15));
    w |= __shfl_xor(w, 1);
    w |= __shfl_xor(w, 2);
    w |= __shfl_xor(w, 4);
    w |= __shfl_xor(w, 8);
    if ((tid & 15) == 0) bits[i >> 4] = ~w;  // inverted: 1 = keep
  }
}

// ------- 128x128 GEMM core, BK=32 dbuf, 512 threads / 8 waves -------
// r1 transform applied to the projection GEMM: same tile, same LDS, same
// staged bytes, but 8 waves/block (wave tile 32x64, acc[2][4]) -> 24
// resident waves/CU at grid 768 (vs 12 with the 4-wave version): the
// per-K-step vmcnt(0)+barrier drain is hidden by 2x the wave pool.
__device__ __forceinline__ void gemm128_w8(const bf16* __restrict__ A,
                                           const bf16* __restrict__ Bt,
                                           bf16* As, bf16* Bs,
                                           int rowBase, int colBase,
                                           f32x4 acc[2][4]) {
  const int tid = threadIdx.x;             // 0..511
  const int lane = tid & 63, w = tid >> 6; // w 0..7
  const int g = lane >> 4, r = lane & 15;

  auto stage = [&](int buf, int s) {
    {
      int c = tid;  // 512 chunks of 8 elems = full 128x32 A tile
      int row = c >> 2, gr = c & 3, sg = gr ^ (row & 3);
      asy16(A + (size_t)(rowBase + row) * 512 + s * 32 + sg * 8,
            As + buf * 4096 + c * 8);
    }
    {
      int c = tid;
      int row = c >> 2, gr = c & 3, sg = gr ^ (row & 3);
      asy16(Bt + (size_t)(colBase + row) * 512 + s * 32 + sg * 8,
            Bs + buf * 4096 + c * 8);
    }
  };

  stage(0, 0);
  int buf = 0;
  const int rbl = (w >> 1) * 32, cbl = (w & 1) * 64;
  for (int s = 0; s < 16; ++s) {
    __syncthreads();
    if (s < 15) stage(buf ^ 1, s + 1);
    const bf16* a0 = As + buf * 4096;
    const bf16* b0 = Bs + buf * 4096;
    short8 af[2], bfr[4];
#pragma unroll
    for (int mt = 0; mt < 2; ++mt) {
      int row = rbl + mt * 16 + r;
      af[mt] = load8(a0 + (row * 4 + (g ^ (row & 3))) * 8);
    }
#pragma unroll
    for (int nt = 0; nt < 4; ++nt) {
      int col = cbl + nt * 16 + r;
      bfr[nt] = load8(b0 + (col * 4 + (g ^ (col & 3))) * 8);
    }
#pragma unroll
    for (int mt = 0; mt < 2; ++mt)
#pragma unroll
      for (int nt = 0; nt < 4; ++nt)
        acc[mt][nt] = __builtin_amdgcn_mfma_f32_16x16x32_bf16(
            af[mt], bfr[nt], acc[mt][nt], 0, 0, 0);
    buf ^= 1;
  }
}

// Fused QKV projection. Q -> [bh][n][64]; K -> Kperm; V -> Vperm.
// XCD-chunked swizzle (neutral, kept). 512 threads / 8 waves (r1 transform);
// scatter epilogue (r9 measured LDS-coalesced == scatter).
__global__ __launch_bounds__(512, 6) void k_proj_qkv(
    const bf16* __restrict__ Xb, const bf16* __restrict__ Wcat,
    bf16* __restrict__ Qb, bf16* __restrict__ Kp, bf16* __restrict__ Vp) {
  const int bid = blockIdx.x;
  const int xcd = bid & 7, idx = bid >> 3;            // idx in [0,96)
  const int rowPanel = (xcd << 3) | (idx & 7);        // [0,64)
  const int colPanel = idx >> 3;                      // [0,12)
  int rowBase = rowPanel * 128, colBase = colPanel * 128;
  __shared__ __align__(16) bf16 As[2 * 4096];
  __shared__ __align__(16) bf16 Bs[2 * 4096];
  f32x4 acc[2][4] = {};
  gemm128_w8(Xb, Wcat, As, Bs, rowBase, colBase, acc);
  const int lane = threadIdx.x & 63, w = threadIdx.x >> 6;
  const int g = lane >> 4, r = lane & 15;
#pragma unroll
  for (int mt = 0; mt < 2; ++mt) {
    int row0 = rowBase + (w >> 1) * 32 + mt * 16 + 4 * g;
    int b = row0 >> 11, n0 = row0 & 2047;
    int kt = n0 >> 6;
#pragma unroll
    for (int nt = 0; nt < 4; ++nt) {
      int col = colBase + (w & 1) * 64 + nt * 16 + r;
      if (col < 512) {
        int hh = col >> 6, dk = col & 63;
        bf16* p0 = Qb + ((size_t)(b * 8 + hh) * 2048 + n0) * 64 + dk;
#pragma unroll
        for (int rr = 0; rr < 4; ++rr)
          p0[rr * 64] = __float2bfloat16(acc[mt][nt][rr]);
      } else if (col < 1024) {
        int hh = (col >> 6) & 7, dk = col & 63;
        int half = dk >> 5, gk = (dk >> 3) & 3, jj = dk & 7;
        int kr = n0 & 63;
        int kc = kr >> 4, r0 = kr & 15;
        bf16* base = Kp + (size_t)(b * 8 + hh) * 131072 + (size_t)kt * 4096 +
                     ((kc * 2 + half) * 4 + gk) * 128 + jj;
#pragma unroll
        for (int rr = 0; rr < 4; ++rr)
          base[(r0 + rr) * 8] = __float2bfloat16(acc[mt][nt][rr]);
      } else {
        int hdv = col - 1024;
        int hh = hdv >> 6, dv = hdv & 63;
        int dvs = dv >> 4, rv = dv & 15;
        int kcol0 = n0 & 63;
        int half = kcol0 >> 5, gv = (kcol0 >> 2) & 3;
        int j0 = ((kcol0 >> 4) & 1) * 4;
        short4b pkv;
#pragma unroll
        for (int rr = 0; rr < 4; ++rr) pkv[rr] = f2b(acc[mt][nt][rr]);
        *reinterpret_cast<short4b*>(
            Vp + (size_t)(b * 8 + hh) * 131072 + (size_t)kt * 4096 +
            (((half * 4 + dvs) * 4 + gv) * 16 + rv) * 8 + j0) = pkv;
      }
    }
  }
}

// Output projection: 64x128 tiles, flat grid 512, XCD swizzle.
// 512 threads / 8 waves (r1 transform): wave tile 16x64, acc[4];
// 16 resident waves/CU (vs 8 with the 4-wave version).
__global__ __launch_bounds__(512, 4) void k_proj_out(
    const bf16* __restrict__ O, const bf16* __restrict__ Wot,
    float* __restrict__ out) {
  const int bid = blockIdx.x;
  const int xcd = bid & 7, idx = bid >> 3;            // idx in [0,64)
  const int rowPanel = (xcd << 4) | (idx & 15);       // [0,128)
  const int colPanel = idx >> 4;                      // [0,4)
  int rowBase = rowPanel * 64, colBase = colPanel * 128;
  __shared__ __align__(16) bf16 As[2 * 2048];
  __shared__ __align__(16) bf16 Bs[2 * 4096];

  const int tid = threadIdx.x;
  const int lane = tid & 63, w = tid >> 6;  // w 0..7
  const int g = lane >> 4, r = lane & 15;

  auto stage = [&](int buf, int s) {
    if (tid < 256) {  // A: 64x32 = 256 chunks (waves 0-3, wave-uniform)
      int c = tid;
      int row = c >> 2, gr = c & 3, sg = gr ^ (row & 3);
      asy16(O + (size_t)(rowBase + row) * 512 + s * 32 + sg * 8,
            As + buf * 2048 + c * 8);
    }
    {
      int c = tid;  // B: 128x32 = 512 chunks
      int row = c >> 2, gr = c & 3, sg = gr ^ (row & 3);
      asy16(Wot + (size_t)(colBase + row) * 512 + s * 32 + sg * 8,
            Bs + buf * 4096 + c * 8);
    }
  };

  f32x4 acc[4] = {};
  stage(0, 0);
  int buf = 0;
  const int rbl = (w >> 1) * 16, cbl = (w & 1) * 64;
  for (int s = 0; s < 16; ++s) {
    __syncthreads();
    if (s < 15) stage(buf ^ 1, s + 1);
    const bf16* a0 = As + buf * 2048;
    const bf16* b0 = Bs + buf * 4096;
    int row = rbl + r;
    short8 af = load8(a0 + (row * 4 + (g ^ (row & 3))) * 8);
    short8 bfr[4];
#pragma unroll
    for (int nt = 0; nt < 4; ++nt) {
      int col = cbl + nt * 16 + r;
      bfr[nt] = load8(b0 + (col * 4 + (g ^ (col & 3))) * 8);
    }
#pragma unroll
    for (int nt = 0; nt < 4; ++nt)
      acc[nt] = __builtin_amdgcn_mfma_f32_16x16x32_bf16(af, bfr[nt], acc[nt],
                                                        0, 0, 0);
    buf ^= 1;
  }

  int row0 = rowBase + (w >> 1) * 16 + 4 * g;
#pragma unroll
  for (int nt = 0; nt < 4; ++nt) {
    int col = colBase + (w & 1) * 64 + nt * 16 + r;
#pragma unroll
    for (int rr = 0; rr < 4; ++rr)
      out[(size_t)(row0 + rr) * 512 + col] = acc[nt][rr];
  }
}

// ---------------- flash attention (identical to r9) ----------------
// grid 512 (XCD-swizzled bh x 16 qt-tiles of 128 rows), 512 thr = 8 waves,
// 16 q-rows/wave. Best measured: 53.6us, VGPR 56.
//  - keep-bit masking (sbfe+and, 2 VALU/elem)
//  - 6x-unrolled parity macro (no register copies), NO setprio
//  - hardware cvt_pk P-pack; max-free exp2 softmax; l via MFMA row-sum
// Triple-buffered LDS, linear copy of fragment-order K/V tiles (all frag
// reads contiguous ds_read_b128, zero conflicts). QK(kt+1) before
// softmax(kt); shuffle-free epilogue.
__global__ __launch_bounds__(512, 4) void k_attn(const bf16* __restrict__ Q,
    const bf16* __restrict__ K, const bf16* __restrict__ V,
    const unsigned long long* __restrict__ MB, bf16* __restrict__ O) {
  const int blin = blockIdx.x;
  const int j = blin >> 3;
  const int bh = (blin & 7) * 4 + (j >> 4);
  const int qt = j & 15;
  const int b = bh >> 3, h = bh & 7;
  const int tid = threadIdx.x;
  const int lane = tid & 63;
  const int wave = tid >> 6;  // 0..7
  const int g = lane >> 4, r = lane & 15;
  const int qbase = qt * 128 + wave * 16;

  __shared__ __align__(16) bf16 Kl[3][4096];
  __shared__ __align__(16) bf16 Vl[3][4096];

  const bf16* Kp = K + (size_t)bh * 131072;
  const bf16* Vp = V + (size_t)bh * 131072;

  short8 qf0, qf1;
  {
    const bf16* Qp = Q + ((size_t)bh * 2048 + qbase + r) * 64;
    qf0 = load8(Qp + g * 8);
    qf1 = load8(Qp + 32 + g * 8);
  }
  const unsigned long long* Mp = MB + ((size_t)b * 2048 + qbase + r) * 32;

  short8 ones;
#pragma unroll
  for (int i = 0; i < 8; ++i) ones[i] = (short)0x3F80;  // bf16 1.0

  f32x4 acc[4] = {};
  f32x4 acc_l = {};

  auto stage = [&](int buf, int kt) {
    const bf16* Kg = Kp + (size_t)kt * 4096;
    const bf16* Vg = Vp + (size_t)kt * 4096;
    asy16(Kg + tid * 8, &Kl[buf][0] + tid * 8);
    asy16(Vg + tid * 8, &Vl[buf][0] + tid * 8);
  };

  auto qk = [&](const bf16* kl, f32x4 stl[4]) {
#pragma unroll
    for (int kc = 0; kc < 4; ++kc) {
      short8 kf0 = load8(kl + ((kc * 2 + 0) * 4 + g) * 128 + r * 8);
      short8 kf1 = load8(kl + ((kc * 2 + 1) * 4 + g) * 128 + r * 8);
      f32x4 z = {};
      z = __builtin_amdgcn_mfma_f32_16x16x32_bf16(kf0, qf0, z, 0, 0, 0);
      stl[kc] = __builtin_amdgcn_mfma_f32_16x16x32_bf16(kf1, qf1, z, 0, 0, 0);
    }
  };

  stage(0, 0);
  stage(1, 1);
  unsigned long long mw0, mw1;
  mw0 = Mp[0];
  __syncthreads();
  f32x4 st0[4], st1[4];
  qk(&Kl[0][0], st0);

  // One iteration. CUR/NXT/STG: buffer indices (period 3). SC/SN, MC/MN:
  // st / mask ping-pong (period 2). All compile-time after 6x unroll.
#define ATTN_ITER(KT, CUR, NXT, STG, SC, SN, MC, MN, DO_STAGE, DO_NEXT)       \
  do {                                                                        \
    __syncthreads();                                                          \
    if (DO_STAGE) stage(STG, (KT) + 2);                                       \
    if (DO_NEXT) MN = Mp[(KT) + 1];                                           \
    if (DO_NEXT) qk(&Kl[NXT][0], SN);                                         \
    unsigned ml = (unsigned)MC >> (4 * g);                                    \
    unsigned mh = (unsigned)(MC >> 32) >> (4 * g);                            \
    float p[16];                                                              \
    _Pragma("unroll") for (int kc = 0; kc < 4; ++kc)                          \
        _Pragma("unroll") for (int rr = 0; rr < 4; ++rr)                      \
      p[kc * 4 + rr] = keepmul(EXP2(SC[kc][rr]), (kc & 2) ? mh : ml,          \
                               ((kc & 1) << 4) + rr);                         \
    u32x4 q0, q1;                                                             \
    _Pragma("unroll") for (int i2 = 0; i2 < 4; ++i2) {                        \
      q0[i2] = cvtpk(p[2 * i2], p[2 * i2 + 1]);                               \
      q1[i2] = cvtpk(p[8 + 2 * i2], p[8 + 2 * i2 + 1]);                       \
    }                                                                         \
    short8 pa0 = __builtin_bit_cast(short8, q0);                              \
    short8 pa1 = __builtin_bit_cast(short8, q1);                              \
    acc_l = __builtin_amdgcn_mfma_f32_16x16x32_bf16(pa0, ones, acc_l, 0, 0, 0); \
    acc_l = __builtin_amdgcn_mfma_f32_16x16x32_bf16(pa1, ones, acc_l, 0, 0, 0); \
    const bf16* vl = &Vl[CUR][0];                                             \
    _Pragma("unroll") for (int dvs = 0; dvs < 4; ++dvs) {                     \
      short8 vb0 = load8(vl + ((0 * 4 + dvs) * 4 + g) * 128 + r * 8);         \
      short8 vb1 = load8(vl + ((1 * 4 + dvs) * 4 + g) * 128 + r * 8);         \
      acc[dvs] = __builtin_amdgcn_mfma_f32_16x16x32_bf16(pa0, vb0, acc[dvs], 0, 0, 0); \
      acc[dvs] = __builtin_amdgcn_mfma_f32_16x16x32_bf16(pa1, vb1, acc[dvs], 0, 0, 0); \
    }                                                                         \
  } while (0)

  for (int t = 0; t < 5; ++t) {
    const int kt = 6 * t;
    ATTN_ITER(kt + 0, 0, 1, 2, st0, st1, mw0, mw1, true, true);
    ATTN_ITER(kt + 1, 1, 2, 0, st1, st0, mw1, mw0, true, true);
    ATTN_ITER(kt + 2, 2, 0, 1, st0, st1, mw0, mw1, true, true);
    ATTN_ITER(kt + 3, 0, 1, 2, st1, st0, mw1, mw0, true, true);
    ATTN_ITER(kt + 4, 1, 2, 0, st0, st1, mw0, mw1, true, true);
    ATTN_ITER(kt + 5, 2, 0, 1, st1, st0, mw1, mw0, true, true);
  }
  // kt = 30, 31 tail (no stage past tile 31; no next-qk at 31)
  ATTN_ITER(30, 0, 1, 2, st0, st1, mw0, mw1, false, true);
  ATTN_ITER(31, 1, 2, 0, st1, st0, mw1, mw0, false, false);
#undef ATTN_ITER

  // shuffle-free epilogue
  float inv[4];
#pragma unroll
  for (int rr = 0; rr < 4; ++rr)
    inv[rr] = (acc_l[rr] > 0.f) ? 1.f / acc_l[rr] : 0.f;
  bf16* Op = O + ((size_t)b * 2048 + qbase + 4 * g) * 512 + h * 64;
#pragma unroll
  for (int dvs = 0; dvs < 4; ++dvs)
#pragma unroll
    for (int rr = 0; rr < 4; ++rr)
      Op[rr * 512 + dvs * 16 + r] = __float2bfloat16(acc[dvs][rr] * inv[rr]);
}

// ---------------- launch ----------------

extern "C" void kernel_launch(void* const* d_in, const int* in_sizes, int n_in,
                              void* d_out, int out_size, void* d_ws, size_t ws_size,
                              hipStream_t stream) {
  const float* q    = (const float*)d_in[0];
  const int*   mask = (const int*)d_in[1];
  const float* Wq   = (const float*)d_in[2];
  const float* Wk   = (const float*)d_in[3];
  const float* Wv   = (const float*)d_in[4];
  const float* Wo   = (const float*)d_in[5];
  float* out = (float*)d_out;

  char* ws = (char*)d_ws;
  const size_t MB1 = 1024 * 1024;
  // Ob aliases Xb: Xb is dead after k_proj_qkv, Ob is written by k_attn.
  bf16* Xb   = (bf16*)(ws + 0);          // 8 MB [8192][512]
  bf16* Ob   = (bf16*)(ws + 0);          // 8 MB [bn][512] (alias of Xb)
  bf16* Qb   = (bf16*)(ws + 8 * MB1);    // 8 MB [bh][n][64]
  bf16* Kpm  = (bf16*)(ws + 16 * MB1);   // 8 MB fragment-order K
  bf16* Vpm  = (bf16*)(ws + 24 * MB1);   // 8 MB fragment-order V
  unsigned long long* Mbits = (unsigned long long*)(ws + 32 * MB1);  // 2 MB
  bf16* Wcat = (bf16*)(ws + 34 * MB1);   // 1.5 MB
  bf16* Wot  = (bf16*)(ws + 34 * MB1 + 1536 * 512 * 2);  // 0.5 MB

  k_prep<<<20736, 256, 0, stream>>>((const float4*)q, (ushort4*)Xb,
                                    Wq, Wk, Wv, Wo, Wcat, Wot,
                                    (const int4*)mask, Mbits);
  k_proj_qkv<<<768, 512, 0, stream>>>(Xb, Wcat, Qb, Kpm, Vpm);
  k_attn<<<512, 512, 0, stream>>>(Qb, Kpm, Vpm, Mbits, Ob);
  k_proj_out<<<512, 512, 0, stream>>>(Ob, Wot, out);
}